// Round 5
// baseline (249.412 us; speedup 1.0000x reference)
//
#include <hip/hip_runtime.h>

// Problem constants (fixed by the reference)
#define E_DIM 1024
#define NH    16
#define HDIM  64
#define BB    2
#define LSEQ  2048
#define MTOT  (BB*LSEQ)   // 4096 tokens

typedef float  f32x4  __attribute__((ext_vector_type(4)));
typedef __bf16 bf16x8 __attribute__((ext_vector_type(8)));
typedef unsigned int   u32x4 __attribute__((ext_vector_type(4)));
typedef unsigned short u16x4 __attribute__((ext_vector_type(4)));
typedef unsigned short u16x8 __attribute__((ext_vector_type(8)));

union U16 {           // 16-byte fragment: 8 bf16
    u32x4  u4;
    bf16x8 b;
};

__device__ inline unsigned short f2bf(float f) {
    union { __bf16 h; unsigned short u; } x;
    x.h = (__bf16)f;
    return x.u;
}

__device__ __forceinline__ float fexp2(float x) {
#if __has_builtin(__builtin_amdgcn_exp2f)
    return __builtin_amdgcn_exp2f(x);   // single v_exp_f32
#else
    return exp2f(x);
#endif
}

// async global->LDS, 16B per lane. LDS dest is wave-uniform base + lane*16.
__device__ __forceinline__ void gload_lds16(const unsigned short* g, unsigned short* l) {
    __builtin_amdgcn_global_load_lds(
        (const __attribute__((address_space(1))) void*)g,
        (__attribute__((address_space(3))) void*)l, 16, 0, 0);
}

// ---------------- fp32 -> bf16 bulk convert, 3 tensors in one launch ----------------
__global__ __launch_bounds__(256) void convert3(
    const float* __restrict__ q, const float* __restrict__ k, const float* __restrict__ v,
    unsigned short* __restrict__ Xq, unsigned short* __restrict__ Xk,
    unsigned short* __restrict__ Xv, int n)
{
    int z = blockIdx.y;
    const float* in = z == 0 ? q : (z == 1 ? k : v);
    unsigned short* out = z == 0 ? Xq : (z == 1 ? Xk : Xv);
    int i = (blockIdx.x * 256 + threadIdx.x) * 4;
    int stride = gridDim.x * 256 * 4;
    for (; i < n; i += stride) {
        f32x4 val = *(const f32x4*)(in + i);
        u16x4 o = { f2bf(val.x), f2bf(val.y), f2bf(val.z), f2bf(val.w) };
        *(u16x4*)(out + i) = o;
    }
}

// ---------------- W [K][N] f32 -> Wt [N][K] bf16, 4 weights in one launch ----------------
__global__ __launch_bounds__(256) void transpose_w4(
    const float* __restrict__ Wq, const float* __restrict__ Wk,
    const float* __restrict__ Wv, const float* __restrict__ Wo,
    unsigned short* __restrict__ Wqt, unsigned short* __restrict__ Wkt,
    unsigned short* __restrict__ Wvt, unsigned short* __restrict__ Wot)
{
    int z = blockIdx.z;
    const float* W = z == 0 ? Wq : (z == 1 ? Wk : (z == 2 ? Wv : Wo));
    unsigned short* Wt = z == 0 ? Wqt : (z == 1 ? Wkt : (z == 2 ? Wvt : Wot));
    __shared__ unsigned short tile[64][80];
    int n0 = blockIdx.x * 64, k0 = blockIdx.y * 64;
    int t = threadIdx.x;
#pragma unroll
    for (int i = 0; i < 4; i++) {
        int idx = i * 256 + t;
        int kr = idx >> 4, nc = (idx & 15) * 4;
        f32x4 val = *(const f32x4*)(W + (size_t)(k0 + kr) * E_DIM + n0 + nc);
        u16x4 o = { f2bf(val.x), f2bf(val.y), f2bf(val.z), f2bf(val.w) };
        *(u16x4*)&tile[kr][nc] = o;
    }
    __syncthreads();
#pragma unroll
    for (int i = 0; i < 2; i++) {
        int idx = i * 256 + t;
        int nr = idx >> 3, kc = (idx & 7) * 8;
        union { unsigned short s[8]; u16x8 v; } pack;
#pragma unroll
        for (int j = 0; j < 8; j++) pack.s[j] = tile[kc + j][nr];
        *(u16x8*)(Wt + (size_t)(n0 + nr) * E_DIM + k0 + kc) = pack.v;
    }
}

// ---------------- batched QKV projection GEMM (z = 0,1,2) ----------------
// z=0,1: out[b,h,l,hd] (head-major [bh][L][64]); z=2: out written TRANSPOSED
// as [bh][64][L] (feeds attention's V^T operand directly; kills transpose_v).
__global__ __launch_bounds__(256) void gemm_qkv(
    const unsigned short* __restrict__ Xq, const unsigned short* __restrict__ Xk,
    const unsigned short* __restrict__ Xv,
    const unsigned short* __restrict__ Wqt, const unsigned short* __restrict__ Wkt,
    const unsigned short* __restrict__ Wvt,
    const float* __restrict__ bqp, const float* __restrict__ bkp, const float* __restrict__ bvp,
    unsigned short* __restrict__ Qh, unsigned short* __restrict__ Kh,
    unsigned short* __restrict__ Vtp, float scaleQ)
{
    int z = blockIdx.z;
    const unsigned short* A  = z == 0 ? Xq  : (z == 1 ? Xk  : Xv);
    const unsigned short* Bt = z == 0 ? Wqt : (z == 1 ? Wkt : Wvt);
    const float* bias        = z == 0 ? bqp : (z == 1 ? bkp : bvp);
    unsigned short* out      = z == 0 ? Qh  : (z == 1 ? Kh  : Vtp);
    float scale              = z == 0 ? scaleQ : 1.0f;

    __shared__ unsigned short Al[128 * 64];
    __shared__ unsigned short Bl[128 * 64];
    int t = threadIdx.x;
    int lane = t & 63, w = t >> 6;
    int qc = lane & 15, kg = lane >> 4;
    int m0 = blockIdx.x * 128, n0 = blockIdx.y * 128;
    int wr = (w >> 1) * 64, wc = (w & 1) * 64;

    int srow = w * 32 + (lane >> 3);
    int scol = (lane & 7) * 8;
    const unsigned short* Ag = A + (size_t)(m0 + srow) * E_DIM + scol;
    const unsigned short* Bg = Bt + (size_t)(n0 + srow) * E_DIM + scol;
    unsigned short* Asl = &Al[(w * 32) * 64];
    unsigned short* Bsl = &Bl[(w * 32) * 64];

    f32x4 acc[4][4];
#pragma unroll
    for (int i = 0; i < 4; i++)
#pragma unroll
        for (int j = 0; j < 4; j++)
            acc[i][j] = {0.f, 0.f, 0.f, 0.f};

    for (int kt = 0; kt < E_DIM / 64; kt++) {
        const unsigned short* Ak = Ag + (kt << 6);
        const unsigned short* Bk = Bg + (kt << 6);
        __syncthreads();
#pragma unroll
        for (int i = 0; i < 4; i++) {
            gload_lds16(Ak + (size_t)i * 8 * E_DIM, Asl + i * 8 * 64);
            gload_lds16(Bk + (size_t)i * 8 * E_DIM, Bsl + i * 8 * 64);
        }
        __syncthreads();
#pragma unroll
        for (int k2 = 0; k2 < 2; k2++) {
            U16 af[4], bg[4];
#pragma unroll
            for (int mi = 0; mi < 4; mi++)
                af[mi].u4 = *(const u32x4*)&Al[(wr + mi * 16 + qc) * 64 + k2 * 32 + kg * 8];
#pragma unroll
            for (int ni = 0; ni < 4; ni++)
                bg[ni].u4 = *(const u32x4*)&Bl[(wc + ni * 16 + qc) * 64 + k2 * 32 + kg * 8];
#pragma unroll
            for (int mi = 0; mi < 4; mi++)
#pragma unroll
                for (int ni = 0; ni < 4; ni++)
                    acc[mi][ni] = __builtin_amdgcn_mfma_f32_16x16x32_bf16(
                        af[mi].b, bg[ni].b, acc[mi][ni], 0, 0, 0);
        }
    }
    // Epilogue. D layout: col n = lane&15, row m = (lane>>4)*4 + r  [m89]
    if (z == 2) {
        // V transposed write: Vt[(b*NH+h)*64 + hd][l], 4 consecutive l per lane
#pragma unroll
        for (int ni = 0; ni < 4; ni++) {
            int n = n0 + wc + ni * 16 + qc;
            float bval = bias[n];
            int h = n >> 6, hd = n & 63;
#pragma unroll
            for (int mi = 0; mi < 4; mi++) {
                int m = m0 + wr + mi * 16 + kg * 4;
                int b = m >> 11, l = m & (LSEQ - 1);
                u16x4 o = { f2bf(acc[mi][ni][0] + bval), f2bf(acc[mi][ni][1] + bval),
                            f2bf(acc[mi][ni][2] + bval), f2bf(acc[mi][ni][3] + bval) };
                *(u16x4*)(out + ((size_t)((b * NH + h) * HDIM + hd)) * LSEQ + l) = o;
            }
        }
    } else {
#pragma unroll
        for (int ni = 0; ni < 4; ni++) {
            int n = n0 + wc + ni * 16 + qc;
            float bval = bias[n];
            int h = n >> 6, hd = n & 63;
#pragma unroll
            for (int mi = 0; mi < 4; mi++) {
#pragma unroll
                for (int r = 0; r < 4; r++) {
                    int m = m0 + wr + mi * 16 + kg * 4 + r;
                    float v = (acc[mi][ni][r] + bval) * scale;
                    int b = m >> 11, l = m & (LSEQ - 1);
                    out[(((size_t)(b * NH + h)) * LSEQ + l) * HDIM + hd] = f2bf(v);
                }
            }
        }
    }
}

// ---------------- O-projection GEMM: 128x64 tile ----------------
__global__ __launch_bounds__(256) void gemm_o(
    const unsigned short* __restrict__ A, const unsigned short* __restrict__ Bt,
    const float* __restrict__ bias, float* __restrict__ outF)
{
    __shared__ unsigned short Al[128 * 64];
    __shared__ unsigned short Bl[64 * 64];
    int t = threadIdx.x;
    int lane = t & 63, w = t >> 6;
    int qc = lane & 15, kg = lane >> 4;
    int m0 = blockIdx.x * 128, n0 = blockIdx.y * 64;
    int wr = (w >> 1) * 64, wc = (w & 1) * 32;

    int srA = w * 32 + (lane >> 3);
    int srB = w * 16 + (lane >> 3);
    int scol = (lane & 7) * 8;
    const unsigned short* Ag = A + (size_t)(m0 + srA) * E_DIM + scol;
    const unsigned short* Bg = Bt + (size_t)(n0 + srB) * E_DIM + scol;
    unsigned short* Asl = &Al[(w * 32) * 64];
    unsigned short* Bsl = &Bl[(w * 16) * 64];

    f32x4 acc[4][2];
#pragma unroll
    for (int i = 0; i < 4; i++)
#pragma unroll
        for (int j = 0; j < 2; j++)
            acc[i][j] = {0.f, 0.f, 0.f, 0.f};

    for (int kt = 0; kt < E_DIM / 64; kt++) {
        const unsigned short* Ak = Ag + (kt << 6);
        const unsigned short* Bk = Bg + (kt << 6);
        __syncthreads();
#pragma unroll
        for (int i = 0; i < 4; i++)
            gload_lds16(Ak + (size_t)i * 8 * E_DIM, Asl + i * 8 * 64);
#pragma unroll
        for (int i = 0; i < 2; i++)
            gload_lds16(Bk + (size_t)i * 8 * E_DIM, Bsl + i * 8 * 64);
        __syncthreads();
#pragma unroll
        for (int k2 = 0; k2 < 2; k2++) {
            U16 af[4], bg[2];
#pragma unroll
            for (int mi = 0; mi < 4; mi++)
                af[mi].u4 = *(const u32x4*)&Al[(wr + mi * 16 + qc) * 64 + k2 * 32 + kg * 8];
#pragma unroll
            for (int ni = 0; ni < 2; ni++)
                bg[ni].u4 = *(const u32x4*)&Bl[(wc + ni * 16 + qc) * 64 + k2 * 32 + kg * 8];
#pragma unroll
            for (int mi = 0; mi < 4; mi++)
#pragma unroll
                for (int ni = 0; ni < 2; ni++)
                    acc[mi][ni] = __builtin_amdgcn_mfma_f32_16x16x32_bf16(
                        af[mi].b, bg[ni].b, acc[mi][ni], 0, 0, 0);
        }
    }
#pragma unroll
    for (int ni = 0; ni < 2; ni++) {
        int n = n0 + wc + ni * 16 + qc;
        float bval = bias[n];
#pragma unroll
        for (int mi = 0; mi < 4; mi++) {
#pragma unroll
            for (int r = 0; r < 4; r++) {
                int m = m0 + wr + mi * 16 + kg * 4 + r;
                outF[(size_t)m * E_DIM + n] = acc[mi][ni][r] + bval;
            }
        }
    }
}

// ---------------- causal flash attention: 4-wave blocks, grid 1024 ----------------
// Qh/Kh: [bh][L][64] bf16 (Q pre-scaled by log2e/8). Vt: [bh][64][L] bf16.
// Block = 4 waves, one bh + one 64-row q-tile (wave w: 16 rows). Grid 1024 =
// 32 bh x 32 q-tiles; per-XCD chunking (4 bh/XCD) + descending-work dispatch
// order (heavy q-tiles first) for backfill balance. K/V staged once per block
// via global_load_lds into double-buffered XOR-swizzled LDS.
// Swapped-operand MFMA: S^T = K.Q^T, ctx^T = V^T.P^T; per-lane softmax.
__global__ __launch_bounds__(256, 3) void attn_causal(
    const unsigned short* __restrict__ Qh, const unsigned short* __restrict__ Kh,
    const unsigned short* __restrict__ Vt, unsigned short* __restrict__ Ctx)
{
    __shared__ unsigned short Kst[2][64 * 64];   // [kv][d], swizzled, 8KB/buf
    __shared__ unsigned short Vst[2][64 * 64];   // [d][kv], swizzled, 8KB/buf
    __shared__ unsigned short Pl[4][16 * 72];    // per-wave P[q][kv], stride 72

    int flat = blockIdx.x;
    int xcd = flat & 7;
    int idx = flat >> 3;                 // 0..127 within XCD stream
    int bh = xcd * 4 + (idx >> 5);       // 4 heads per XCD -> K/V fit its L2
    int qt = 31 - (idx & 31);            // heavy q-tiles dispatched first

    int t = threadIdx.x;
    int w = t >> 6, lane = t & 63;
    int qc = lane & 15, kg = lane >> 4;
    int q0w = qt * 64 + w * 16;
    int nt = qt + 1;                     // kv tiles (64-wide)

    const unsigned short* Qb  = Qh + (size_t)bh * LSEQ * HDIM;
    const unsigned short* Kb  = Kh + (size_t)bh * LSEQ * HDIM;
    const unsigned short* Vbt = Vt + (size_t)bh * HDIM * LSEQ;
    int b = bh >> 4, h = bh & 15;
    unsigned short* Cb = Ctx + ((size_t)b * LSEQ) * E_DIM + h * HDIM;

    // staging constants: wave w covers rows [16w,16w+16); lane stages 16B
    int lrow = lane >> 3;                      // 0..7
    int c16s = ((lane & 7) ^ lrow) * 8;        // pre-swizzled source col (elems)
    int krow = 16 * w + lrow;
    unsigned short* KstW0 = &Kst[0][w * 1024];
    unsigned short* KstW1 = &Kst[1][w * 1024];
    unsigned short* VstW0 = &Vst[0][w * 1024];
    unsigned short* VstW1 = &Vst[1][w * 1024];

    unsigned short* Pw = &Pl[w][0];
    unsigned short* Pst = Pw + qc * 72 + kg * 4;        // store: row q=qc, col f*16+kg*4
    const unsigned short* Pld = Pw + qc * 72 + kg * 8;  // load B-frag: col q=qc, k=kv

    int sw = (qc & 7) * 8;   // read-side swizzle term

    // Q B-frags (col=q=lane&15, k=d=kg*8+j)
    U16 qf0, qf1;
    qf0.u4 = *(const u32x4*)(Qb + (size_t)(q0w + qc) * HDIM + kg * 8);
    qf1.u4 = *(const u32x4*)(Qb + (size_t)(q0w + qc) * HDIM + 32 + kg * 8);

    f32x4 ctx[4];
#pragma unroll
    for (int df = 0; df < 4; df++) ctx[df] = {0.f, 0.f, 0.f, 0.f};
    float mrun = -1e30f, lrun = 0.f;

    // prologue: stage tile 0 into buffer 0
    gload_lds16(Kb + (size_t)krow * HDIM + c16s, KstW0);
    gload_lds16(Kb + (size_t)(krow + 8) * HDIM + c16s, KstW0 + 512);
    gload_lds16(Vbt + (size_t)krow * LSEQ + c16s, VstW0);
    gload_lds16(Vbt + (size_t)(krow + 8) * LSEQ + c16s, VstW0 + 512);
    __syncthreads();   // drains vmcnt: tile 0 visible

    for (int tt = 0; tt < nt; tt++) {
        int kv0 = tt << 6;
        int cur = tt & 1;
        // stage next tile into the other buffer (issued early, drained at barrier)
        if (tt + 1 < nt) {
            int kvn = kv0 + 64;
            unsigned short* Kd = cur ? KstW0 : KstW1;
            unsigned short* Vd = cur ? VstW0 : VstW1;
            gload_lds16(Kb + (size_t)(kvn + krow) * HDIM + c16s, Kd);
            gload_lds16(Kb + (size_t)(kvn + krow + 8) * HDIM + c16s, Kd + 512);
            gload_lds16(Vbt + (size_t)krow * LSEQ + kvn + c16s, Vd);
            gload_lds16(Vbt + (size_t)(krow + 8) * LSEQ + kvn + c16s, Vd + 512);
        }
        const unsigned short* Kc = &Kst[cur][0];
        const unsigned short* Vc = &Vst[cur][0];
        // ---- S^T = K Q^T : rows kv = f*16+kg*4+r, col q = qc ----
        f32x4 s[4];
        __builtin_amdgcn_s_setprio(1);
#pragma unroll
        for (int f = 0; f < 4; f++) {
            U16 k0_, k1_;   // A-frag row kv=f*16+qc, k=d (2 halves)
            k0_.u4 = *(const u32x4*)&Kc[(f * 16 + qc) * 64 + ((kg * 8) ^ sw)];
            k1_.u4 = *(const u32x4*)&Kc[(f * 16 + qc) * 64 + ((32 + kg * 8) ^ sw)];
            f32x4 z = {0.f, 0.f, 0.f, 0.f};
            z = __builtin_amdgcn_mfma_f32_16x16x32_bf16(k0_.b, qf0.b, z, 0, 0, 0);
            z = __builtin_amdgcn_mfma_f32_16x16x32_bf16(k1_.b, qf1.b, z, 0, 0, 0);
            s[f] = z;
        }
        __builtin_amdgcn_s_setprio(0);
        // ---- causal mask (diagonal tile only) ----
        if (kv0 + 63 > q0w) {
            int qi = q0w + qc;
#pragma unroll
            for (int f = 0; f < 4; f++) {
#pragma unroll
                for (int r = 0; r < 4; r++) {
                    if (kv0 + f * 16 + kg * 4 + r > qi) s[f][r] = -1e30f;
                }
            }
        }
        // ---- per-lane softmax (16 regs) + 2 cross-lane steps ----
        float m0_ = fmaxf(fmaxf(s[0][0], s[0][1]), fmaxf(s[0][2], s[0][3]));
        float m1_ = fmaxf(fmaxf(s[1][0], s[1][1]), fmaxf(s[1][2], s[1][3]));
        float m2_ = fmaxf(fmaxf(s[2][0], s[2][1]), fmaxf(s[2][2], s[2][3]));
        float m3_ = fmaxf(fmaxf(s[3][0], s[3][1]), fmaxf(s[3][2], s[3][3]));
        float tm = fmaxf(fmaxf(m0_, m1_), fmaxf(m2_, m3_));
        tm = fmaxf(tm, __shfl_xor(tm, 16));
        tm = fmaxf(tm, __shfl_xor(tm, 32));
        float mn;
        if (__all(tm - mrun <= 8.0f)) {       // T13 defer-max
            mn = mrun;
        } else {
            mn = fmaxf(mrun, tm);
            float sc = fexp2(mrun - mn);
            mrun = mn;
            lrun *= sc;
#pragma unroll
            for (int df = 0; df < 4; df++) ctx[df] *= sc;
        }
#pragma unroll
        for (int f = 0; f < 4; f++)
#pragma unroll
            for (int r = 0; r < 4; r++)
                s[f][r] = fexp2(s[f][r] - mn);
        float rs = ((s[0][0] + s[0][1]) + (s[0][2] + s[0][3]))
                 + ((s[1][0] + s[1][1]) + (s[1][2] + s[1][3]))
                 + ((s[2][0] + s[2][1]) + (s[2][2] + s[2][3]))
                 + ((s[3][0] + s[3][1]) + (s[3][2] + s[3][3]));
        rs += __shfl_xor(rs, 16);
        rs += __shfl_xor(rs, 32);
        lrun += rs;
        // ---- store P[q=qc][kv] ----
#pragma unroll
        for (int f = 0; f < 4; f++) {
            u16x4 p = { f2bf(s[f][0]), f2bf(s[f][1]), f2bf(s[f][2]), f2bf(s[f][3]) };
            *(u16x4*)(Pst + f * 16) = p;
        }
        // ---- ctx^T += V^T P^T ----
        __builtin_amdgcn_s_setprio(1);
#pragma unroll
        for (int k2 = 0; k2 < 2; k2++) {
            U16 ap;
            ap.u4 = *(const u32x4*)(Pld + k2 * 32);
#pragma unroll
            for (int df = 0; df < 4; df++) {
                U16 vf;   // A-frag row d=df*16+qc, k=kv (half k2)
                vf.u4 = *(const u32x4*)&Vc[(df * 16 + qc) * 64 +
                                           ((k2 * 32 + kg * 8) ^ sw)];
                ctx[df] = __builtin_amdgcn_mfma_f32_16x16x32_bf16(
                    vf.b, ap.b, ctx[df], 0, 0, 0);
            }
        }
        __builtin_amdgcn_s_setprio(0);
        __syncthreads();   // drains staging vmcnt + separates buffers
    }
    // ---- normalize + store: lane holds q = q0w+qc, d = df*16+kg*4+r ----
    float inv = 1.f / lrun;
    unsigned short* Cq = Cb + (size_t)(q0w + qc) * E_DIM;
#pragma unroll
    for (int df = 0; df < 4; df++) {
        u16x4 o = { f2bf(ctx[df][0] * inv), f2bf(ctx[df][1] * inv),
                    f2bf(ctx[df][2] * inv), f2bf(ctx[df][3] * inv) };
        *(u16x4*)(Cq + df * 16 + kg * 4) = o;
    }
}

// ---------------- launcher ----------------
extern "C" void kernel_launch(void* const* d_in, const int* in_sizes, int n_in,
                              void* d_out, int out_size, void* d_ws, size_t ws_size,
                              hipStream_t stream)
{
    (void)in_sizes; (void)n_in; (void)out_size; (void)ws_size;
    const float* query = (const float*)d_in[0];
    const float* key_  = (const float*)d_in[1];
    const float* value = (const float*)d_in[2];
    const float* Wq = (const float*)d_in[5];
    const float* bq = (const float*)d_in[6];
    const float* Wk = (const float*)d_in[7];
    const float* bk = (const float*)d_in[8];
    const float* Wv = (const float*)d_in[9];
    const float* bv = (const float*)d_in[10];
    const float* Wo = (const float*)d_in[11];
    const float* bo = (const float*)d_in[12];
    float* out = (float*)d_out;

    char* ws = (char*)d_ws;
    const size_t MB = 1024 * 1024;
    unsigned short* Xq  = (unsigned short*)(ws + 0 * MB);
    unsigned short* Xk  = (unsigned short*)(ws + 8 * MB);
    unsigned short* Xv  = (unsigned short*)(ws + 16 * MB);
    unsigned short* Wqt = (unsigned short*)(ws + 24 * MB);
    unsigned short* Wkt = (unsigned short*)(ws + 26 * MB);
    unsigned short* Wvt = (unsigned short*)(ws + 28 * MB);
    unsigned short* Wot = (unsigned short*)(ws + 30 * MB);
    unsigned short* Qh  = (unsigned short*)(ws + 32 * MB);
    unsigned short* Kh  = (unsigned short*)(ws + 40 * MB);
    unsigned short* Vtp = (unsigned short*)(ws + 56 * MB);
    unsigned short* Ctx = (unsigned short*)(ws + 0 * MB);  // reuse Xq

    const int nElem = MTOT * E_DIM;
    convert3<<<dim3(512, 3), 256, 0, stream>>>(query, key_, value, Xq, Xk, Xv, nElem);
    transpose_w4<<<dim3(16, 16, 4), 256, 0, stream>>>(Wq, Wk, Wv, Wo,
                                                      Wqt, Wkt, Wvt, Wot);

    const float SCALE_Q = 0.18033688011112042f;  // log2(e) / sqrt(HD)=8
    gemm_qkv<<<dim3(32, 8, 3), 256, 0, stream>>>(Xq, Xk, Xv, Wqt, Wkt, Wvt,
                                                 bq, bk, bv, Qh, Kh, Vtp, SCALE_Q);

    attn_causal<<<dim3(1024), 256, 0, stream>>>(Qh, Kh, Vtp, Ctx);

    gemm_o<<<dim3(32, 16), 256, 0, stream>>>(Ctx, Wot, bo, out);
}

// Round 6
// 236.819 us; speedup vs baseline: 1.0532x; 1.0532x over previous
//
#include <hip/hip_runtime.h>

// Problem constants (fixed by the reference)
#define E_DIM 1024
#define NH    16
#define HDIM  64
#define BB    2
#define LSEQ  2048
#define MTOT  (BB*LSEQ)   // 4096 tokens

typedef float  f32x4  __attribute__((ext_vector_type(4)));
typedef __bf16 bf16x8 __attribute__((ext_vector_type(8)));
typedef unsigned int   u32x4 __attribute__((ext_vector_type(4)));
typedef unsigned short u16x4 __attribute__((ext_vector_type(4)));
typedef unsigned short u16x8 __attribute__((ext_vector_type(8)));

union U16 {           // 16-byte fragment: 8 bf16
    u32x4  u4;
    bf16x8 b;
};

__device__ inline unsigned short f2bf(float f) {
    union { __bf16 h; unsigned short u; } x;
    x.h = (__bf16)f;
    return x.u;
}

__device__ __forceinline__ float fexp2(float x) {
#if __has_builtin(__builtin_amdgcn_exp2f)
    return __builtin_amdgcn_exp2f(x);   // single v_exp_f32
#else
    return exp2f(x);
#endif
}

// async global->LDS, 16B per lane. LDS dest is wave-uniform base + lane*16.
__device__ __forceinline__ void gload_lds16(const unsigned short* g, unsigned short* l) {
    __builtin_amdgcn_global_load_lds(
        (const __attribute__((address_space(1))) void*)g,
        (__attribute__((address_space(3))) void*)l, 16, 0, 0);
}

// ---------------- setup: fp32->bf16 converts (3 tensors) + W transposes (4) ----------------
// blocks [0,1536): convert (512/tensor); [1536,2560): transpose_w (256/weight).
__global__ __launch_bounds__(256) void setup(
    const float* __restrict__ q, const float* __restrict__ k, const float* __restrict__ v,
    unsigned short* __restrict__ Xq, unsigned short* __restrict__ Xk,
    unsigned short* __restrict__ Xv,
    const float* __restrict__ Wq, const float* __restrict__ Wk,
    const float* __restrict__ Wv, const float* __restrict__ Wo,
    unsigned short* __restrict__ Wqt, unsigned short* __restrict__ Wkt,
    unsigned short* __restrict__ Wvt, unsigned short* __restrict__ Wot)
{
    __shared__ unsigned short tile[64][80];
    int bx = blockIdx.x;
    int t = threadIdx.x;
    if (bx < 1536) {
        int z = bx >> 9;             // 0..2
        int blk = bx & 511;
        const float* in = z == 0 ? q : (z == 1 ? k : v);
        unsigned short* out = z == 0 ? Xq : (z == 1 ? Xk : Xv);
        const int n = MTOT * E_DIM;
        int i = (blk * 256 + t) * 4;
        const int stride = 512 * 256 * 4;
        for (; i < n; i += stride) {
            f32x4 val = *(const f32x4*)(in + i);
            u16x4 o = { f2bf(val.x), f2bf(val.y), f2bf(val.z), f2bf(val.w) };
            *(u16x4*)(out + i) = o;
        }
    } else {
        int r = bx - 1536;
        int z = r >> 8;              // 0..3
        int g = r & 255;
        const float* W = z == 0 ? Wq : (z == 1 ? Wk : (z == 2 ? Wv : Wo));
        unsigned short* Wt = z == 0 ? Wqt : (z == 1 ? Wkt : (z == 2 ? Wvt : Wot));
        int n0 = (g & 15) * 64, k0 = (g >> 4) * 64;
#pragma unroll
        for (int i = 0; i < 4; i++) {
            int idx = i * 256 + t;
            int kr = idx >> 4, nc = (idx & 15) * 4;
            f32x4 val = *(const f32x4*)(W + (size_t)(k0 + kr) * E_DIM + n0 + nc);
            u16x4 o = { f2bf(val.x), f2bf(val.y), f2bf(val.z), f2bf(val.w) };
            *(u16x4*)&tile[kr][nc] = o;
        }
        __syncthreads();
#pragma unroll
        for (int i = 0; i < 2; i++) {
            int idx = i * 256 + t;
            int nr = idx >> 3, kc = (idx & 7) * 8;
            union { unsigned short s[8]; u16x8 v; } pack;
#pragma unroll
            for (int j = 0; j < 8; j++) pack.s[j] = tile[kc + j][nr];
            *(u16x8*)(Wt + (size_t)(n0 + nr) * E_DIM + k0 + kc) = pack.v;
        }
    }
}

// ---------------- batched QKV projection GEMM (z = 0,1,2) ----------------
// z=0,1: out[b,h,l,hd] (head-major [bh][L][64]); z=2: out written TRANSPOSED
// as [bh][64][L] via LDS-staged coalesced epilogue (feeds attention's V^T).
__global__ __launch_bounds__(256) void gemm_qkv(
    const unsigned short* __restrict__ Xq, const unsigned short* __restrict__ Xk,
    const unsigned short* __restrict__ Xv,
    const unsigned short* __restrict__ Wqt, const unsigned short* __restrict__ Wkt,
    const unsigned short* __restrict__ Wvt,
    const float* __restrict__ bqp, const float* __restrict__ bkp, const float* __restrict__ bvp,
    unsigned short* __restrict__ Qh, unsigned short* __restrict__ Kh,
    unsigned short* __restrict__ Vtp, float scaleQ)
{
    int z = blockIdx.z;
    const unsigned short* A  = z == 0 ? Xq  : (z == 1 ? Xk  : Xv);
    const unsigned short* Bt = z == 0 ? Wqt : (z == 1 ? Wkt : Wvt);
    const float* bias        = z == 0 ? bqp : (z == 1 ? bkp : bvp);
    unsigned short* out      = z == 0 ? Qh  : (z == 1 ? Kh  : Vtp);
    float scale              = z == 0 ? scaleQ : 1.0f;

    __shared__ unsigned short Sh[128 * 128];   // staging (Al|Bl) + z==2 transpose buf
    unsigned short* Al = Sh;
    unsigned short* Bl = Sh + 128 * 64;
    int t = threadIdx.x;
    int lane = t & 63, w = t >> 6;
    int qc = lane & 15, kg = lane >> 4;
    int m0 = blockIdx.x * 128, n0 = blockIdx.y * 128;
    int wr = (w >> 1) * 64, wc = (w & 1) * 64;

    int srow = w * 32 + (lane >> 3);
    int scol = (lane & 7) * 8;
    const unsigned short* Ag = A + (size_t)(m0 + srow) * E_DIM + scol;
    const unsigned short* Bg = Bt + (size_t)(n0 + srow) * E_DIM + scol;
    unsigned short* Asl = &Al[(w * 32) * 64];
    unsigned short* Bsl = &Bl[(w * 32) * 64];

    f32x4 acc[4][4];
#pragma unroll
    for (int i = 0; i < 4; i++)
#pragma unroll
        for (int j = 0; j < 4; j++)
            acc[i][j] = {0.f, 0.f, 0.f, 0.f};

    for (int kt = 0; kt < E_DIM / 64; kt++) {
        const unsigned short* Ak = Ag + (kt << 6);
        const unsigned short* Bk = Bg + (kt << 6);
        __syncthreads();
#pragma unroll
        for (int i = 0; i < 4; i++) {
            gload_lds16(Ak + (size_t)i * 8 * E_DIM, Asl + i * 8 * 64);
            gload_lds16(Bk + (size_t)i * 8 * E_DIM, Bsl + i * 8 * 64);
        }
        __syncthreads();
#pragma unroll
        for (int k2 = 0; k2 < 2; k2++) {
            U16 af[4], bg[4];
#pragma unroll
            for (int mi = 0; mi < 4; mi++)
                af[mi].u4 = *(const u32x4*)&Al[(wr + mi * 16 + qc) * 64 + k2 * 32 + kg * 8];
#pragma unroll
            for (int ni = 0; ni < 4; ni++)
                bg[ni].u4 = *(const u32x4*)&Bl[(wc + ni * 16 + qc) * 64 + k2 * 32 + kg * 8];
#pragma unroll
            for (int mi = 0; mi < 4; mi++)
#pragma unroll
                for (int ni = 0; ni < 4; ni++)
                    acc[mi][ni] = __builtin_amdgcn_mfma_f32_16x16x32_bf16(
                        af[mi].b, bg[ni].b, acc[mi][ni], 0, 0, 0);
        }
    }
    // Epilogue. D layout: col n = lane&15, row m = (lane>>4)*4 + r  [m89]
    if (z == 2) {
        // V^T: stage [n'][l] tile in LDS (XOR-swizzled), then coalesced writeout.
        __syncthreads();   // K-loop LDS readers done before overwrite
#pragma unroll
        for (int ni = 0; ni < 4; ni++) {
            int np = wc + ni * 16 + qc;            // tile-local n'
            float bval = bias[n0 + np];
#pragma unroll
            for (int mi = 0; mi < 4; mi++) {
                int lc = wr + mi * 16 + kg * 4;    // tile-local l base
                u16x4 o = { f2bf(acc[mi][ni][0] + bval), f2bf(acc[mi][ni][1] + bval),
                            f2bf(acc[mi][ni][2] + bval), f2bf(acc[mi][ni][3] + bval) };
                *(u16x4*)&Sh[np * 128 + (lc ^ ((np & 7) << 3))] = o;
            }
        }
        __syncthreads();
        int l0 = m0 & (LSEQ - 1);
        int b_ = m0 >> 11;
        unsigned short* Vo = out + ((size_t)(b_ * 1024 + n0)) * LSEQ + l0;
#pragma unroll
        for (int i = 0; i < 8; i++) {
            int idx = i * 256 + t;
            int row = idx >> 4;              // n' 0..127
            int col = (idx & 15) * 8;        // l col
            u32x4 vv = *(const u32x4*)&Sh[row * 128 + (col ^ ((row & 7) << 3))];
            *(u32x4*)(Vo + (size_t)row * LSEQ + col) = vv;
        }
    } else {
#pragma unroll
        for (int ni = 0; ni < 4; ni++) {
            int n = n0 + wc + ni * 16 + qc;
            float bval = bias[n];
            int h = n >> 6, hd = n & 63;
#pragma unroll
            for (int mi = 0; mi < 4; mi++) {
#pragma unroll
                for (int r = 0; r < 4; r++) {
                    int m = m0 + wr + mi * 16 + kg * 4 + r;
                    float v = (acc[mi][ni][r] + bval) * scale;
                    int b = m >> 11, l = m & (LSEQ - 1);
                    out[(((size_t)(b * NH + h)) * LSEQ + l) * HDIM + hd] = f2bf(v);
                }
            }
        }
    }
}

// ---------------- O-projection GEMM: 128x64 tile ----------------
__global__ __launch_bounds__(256) void gemm_o(
    const unsigned short* __restrict__ A, const unsigned short* __restrict__ Bt,
    const float* __restrict__ bias, float* __restrict__ outF)
{
    __shared__ unsigned short Al[128 * 64];
    __shared__ unsigned short Bl[64 * 64];
    int t = threadIdx.x;
    int lane = t & 63, w = t >> 6;
    int qc = lane & 15, kg = lane >> 4;
    int m0 = blockIdx.x * 128, n0 = blockIdx.y * 64;
    int wr = (w >> 1) * 64, wc = (w & 1) * 32;

    int srA = w * 32 + (lane >> 3);
    int srB = w * 16 + (lane >> 3);
    int scol = (lane & 7) * 8;
    const unsigned short* Ag = A + (size_t)(m0 + srA) * E_DIM + scol;
    const unsigned short* Bg = Bt + (size_t)(n0 + srB) * E_DIM + scol;
    unsigned short* Asl = &Al[(w * 32) * 64];
    unsigned short* Bsl = &Bl[(w * 16) * 64];

    f32x4 acc[4][2];
#pragma unroll
    for (int i = 0; i < 4; i++)
#pragma unroll
        for (int j = 0; j < 2; j++)
            acc[i][j] = {0.f, 0.f, 0.f, 0.f};

    for (int kt = 0; kt < E_DIM / 64; kt++) {
        const unsigned short* Ak = Ag + (kt << 6);
        const unsigned short* Bk = Bg + (kt << 6);
        __syncthreads();
#pragma unroll
        for (int i = 0; i < 4; i++)
            gload_lds16(Ak + (size_t)i * 8 * E_DIM, Asl + i * 8 * 64);
#pragma unroll
        for (int i = 0; i < 2; i++)
            gload_lds16(Bk + (size_t)i * 8 * E_DIM, Bsl + i * 8 * 64);
        __syncthreads();
#pragma unroll
        for (int k2 = 0; k2 < 2; k2++) {
            U16 af[4], bg[2];
#pragma unroll
            for (int mi = 0; mi < 4; mi++)
                af[mi].u4 = *(const u32x4*)&Al[(wr + mi * 16 + qc) * 64 + k2 * 32 + kg * 8];
#pragma unroll
            for (int ni = 0; ni < 2; ni++)
                bg[ni].u4 = *(const u32x4*)&Bl[(wc + ni * 16 + qc) * 64 + k2 * 32 + kg * 8];
#pragma unroll
            for (int mi = 0; mi < 4; mi++)
#pragma unroll
                for (int ni = 0; ni < 2; ni++)
                    acc[mi][ni] = __builtin_amdgcn_mfma_f32_16x16x32_bf16(
                        af[mi].b, bg[ni].b, acc[mi][ni], 0, 0, 0);
        }
    }
#pragma unroll
    for (int ni = 0; ni < 2; ni++) {
        int n = n0 + wc + ni * 16 + qc;
        float bval = bias[n];
#pragma unroll
        for (int mi = 0; mi < 4; mi++) {
#pragma unroll
            for (int r = 0; r < 4; r++) {
                int m = m0 + wr + mi * 16 + kg * 4 + r;
                outF[(size_t)m * E_DIM + n] = acc[mi][ni][r] + bval;
            }
        }
    }
}

// ---------------- causal flash attention: block-cooperative LDS-staged (R4) ----------------
// Qh/Kh: [bh][L][64] bf16 (Q pre-scaled by log2e/8). Vt: [bh][64][L] bf16.
// Grid 256 linear, 512 threads (8 waves). Block owns bh = flat>>3 and processes
// q-blocks qb = pr (pass 0) and 15-pr (pass 1), 128 rows each; wave w gets 16 rows.
// K/V kv-tiles (64x64 bf16, 8KB) staged once per block via global_load_lds into
// double-buffered swizzled LDS (pre-swizzled global source, swizzled ds_read).
// Swapped-operand MFMA: S^T = K.Q^T, ctx^T = V^T.P^T; per-lane softmax.
__global__ __launch_bounds__(512, 2) void attn_causal(
    const unsigned short* __restrict__ Qh, const unsigned short* __restrict__ Kh,
    const unsigned short* __restrict__ Vt, unsigned short* __restrict__ Ctx)
{
    __shared__ unsigned short Kst[2][64 * 64];   // [kv][d], swizzled, 8KB/buf
    __shared__ unsigned short Vst[2][64 * 64];   // [d][kv], swizzled, 8KB/buf
    __shared__ unsigned short Pl[8][16 * 72];    // per-wave P[q][kv], stride 72

    // XCD chunking: XCD k gets flat in [32k,32k+32) -> bh in [4k,4k+4): K/V fit L2
    int flat_hw = blockIdx.x;
    int flat = (flat_hw & 7) * 32 + (flat_hw >> 3);
    int bh = flat >> 3;          // 0..31
    int pr = flat & 7;           // pair id: q-blocks pr and 15-pr

    int t = threadIdx.x;
    int w = t >> 6, lane = t & 63;
    int qc = lane & 15, kg = lane >> 4;

    const unsigned short* Qb  = Qh + (size_t)bh * LSEQ * HDIM;
    const unsigned short* Kb  = Kh + (size_t)bh * LSEQ * HDIM;
    const unsigned short* Vbt = Vt + (size_t)bh * HDIM * LSEQ;
    int b = bh >> 4, h = bh & 15;
    unsigned short* Cb = Ctx + ((size_t)b * LSEQ) * E_DIM + h * HDIM;

    // staging lane constants: lane stages 16B of row (8w+lrow), swizzled col
    int lrow = lane >> 3;                      // 0..7
    int c16s = ((lane & 7) ^ lrow) * 8;        // pre-swizzled source col (elems)
    int krow = 8 * w + lrow;                   // tile-local row this lane stages
    unsigned short* KstW0 = &Kst[0][w * 512];  // wave-uniform LDS bases
    unsigned short* KstW1 = &Kst[1][w * 512];
    unsigned short* VstW0 = &Vst[0][w * 512];
    unsigned short* VstW1 = &Vst[1][w * 512];

    unsigned short* Pw = &Pl[w][0];
    unsigned short* Pst = Pw + qc * 72 + kg * 4;        // store: row q=qc, col f*16+kg*4
    const unsigned short* Pld = Pw + qc * 72 + kg * 8;  // load B-frag: col q=qc, k=kv

    int sw = (qc & 7) * 8;   // read-side swizzle term for row qc within 16-row frags

    for (int pass = 0; pass < 2; pass++) {
        int qb = pass ? (15 - pr) : pr;       // q-block 0..15 (128 rows)
        int q0w = qb * 128 + w * 16;          // this wave's first q row
        int nt = 2 * qb + 2;                  // kv tiles for the block (uniform)
        int nta = (q0w + 79) >> 6;            // active tiles for this wave

        // Q B-frags (col=q=lane&15, k=d=kg*8+j)
        U16 qf0, qf1;
        qf0.u4 = *(const u32x4*)(Qb + (size_t)(q0w + qc) * HDIM + kg * 8);
        qf1.u4 = *(const u32x4*)(Qb + (size_t)(q0w + qc) * HDIM + 32 + kg * 8);

        f32x4 ctx[4];
#pragma unroll
        for (int df = 0; df < 4; df++) ctx[df] = {0.f, 0.f, 0.f, 0.f};
        float mrun = -1e30f, lrun = 0.f;

        // prologue: stage tile 0 into buffer 0
        gload_lds16(Kb + (size_t)krow * HDIM + c16s, KstW0);
        gload_lds16(Vbt + (size_t)krow * LSEQ + c16s, VstW0);
        __syncthreads();   // drains vmcnt: tile 0 visible

        for (int tt = 0; tt < nt; tt++) {
            int kv0 = tt << 6;
            int cur = tt & 1;
            // stage next tile into the other buffer (async; drains at barrier)
            if (tt + 1 < nt) {
                int kvn = kv0 + 64;
                gload_lds16(Kb + (size_t)(kvn + krow) * HDIM + c16s,
                            cur ? KstW0 : KstW1);
                gload_lds16(Vbt + (size_t)krow * LSEQ + kvn + c16s,
                            cur ? VstW0 : VstW1);
            }
            if (tt < nta) {
                const unsigned short* Kc = &Kst[cur][0];
                const unsigned short* Vc = &Vst[cur][0];
                // ---- S^T = K Q^T : rows kv = f*16+kg*4+r, col q = qc ----
                f32x4 s[4];
#pragma unroll
                for (int f = 0; f < 4; f++) {
                    U16 k0_, k1_;   // A-frag row kv=f*16+qc, k=d (2 halves)
                    k0_.u4 = *(const u32x4*)&Kc[(f * 16 + qc) * 64 + ((kg * 8) ^ sw)];
                    k1_.u4 = *(const u32x4*)&Kc[(f * 16 + qc) * 64 + ((32 + kg * 8) ^ sw)];
                    f32x4 z = {0.f, 0.f, 0.f, 0.f};
                    z = __builtin_amdgcn_mfma_f32_16x16x32_bf16(k0_.b, qf0.b, z, 0, 0, 0);
                    z = __builtin_amdgcn_mfma_f32_16x16x32_bf16(k1_.b, qf1.b, z, 0, 0, 0);
                    s[f] = z;
                }
                // ---- causal mask (diagonal tiles only) ----
                if (kv0 + 63 > q0w) {
                    int qi = q0w + qc;
#pragma unroll
                    for (int f = 0; f < 4; f++) {
#pragma unroll
                        for (int r = 0; r < 4; r++) {
                            if (kv0 + f * 16 + kg * 4 + r > qi) s[f][r] = -1e30f;
                        }
                    }
                }
                // ---- per-lane softmax (16 regs) + 2 cross-lane steps ----
                float m0_ = fmaxf(fmaxf(s[0][0], s[0][1]), fmaxf(s[0][2], s[0][3]));
                float m1_ = fmaxf(fmaxf(s[1][0], s[1][1]), fmaxf(s[1][2], s[1][3]));
                float m2_ = fmaxf(fmaxf(s[2][0], s[2][1]), fmaxf(s[2][2], s[2][3]));
                float m3_ = fmaxf(fmaxf(s[3][0], s[3][1]), fmaxf(s[3][2], s[3][3]));
                float tm = fmaxf(fmaxf(m0_, m1_), fmaxf(m2_, m3_));
                tm = fmaxf(tm, __shfl_xor(tm, 16));
                tm = fmaxf(tm, __shfl_xor(tm, 32));
                float mn;
                if (__all(tm - mrun <= 8.0f)) {       // T13 defer-max
                    mn = mrun;
                } else {
                    mn = fmaxf(mrun, tm);
                    float sc = fexp2(mrun - mn);
                    mrun = mn;
                    lrun *= sc;
#pragma unroll
                    for (int df = 0; df < 4; df++) ctx[df] *= sc;
                }
#pragma unroll
                for (int f = 0; f < 4; f++)
#pragma unroll
                    for (int r = 0; r < 4; r++)
                        s[f][r] = fexp2(s[f][r] - mn);
                float rs = ((s[0][0] + s[0][1]) + (s[0][2] + s[0][3]))
                         + ((s[1][0] + s[1][1]) + (s[1][2] + s[1][3]))
                         + ((s[2][0] + s[2][1]) + (s[2][2] + s[2][3]))
                         + ((s[3][0] + s[3][1]) + (s[3][2] + s[3][3]));
                rs += __shfl_xor(rs, 16);
                rs += __shfl_xor(rs, 32);
                lrun += rs;
                // ---- store P[q=qc][kv] ----
#pragma unroll
                for (int f = 0; f < 4; f++) {
                    u16x4 p = { f2bf(s[f][0]), f2bf(s[f][1]), f2bf(s[f][2]), f2bf(s[f][3]) };
                    *(u16x4*)(Pst + f * 16) = p;
                }
                // ---- ctx^T += V^T P^T ----
#pragma unroll
                for (int k2 = 0; k2 < 2; k2++) {
                    U16 ap;
                    ap.u4 = *(const u32x4*)(Pld + k2 * 32);
#pragma unroll
                    for (int df = 0; df < 4; df++) {
                        U16 vf;   // A-frag row d=df*16+qc, k=kv (half k2)
                        vf.u4 = *(const u32x4*)&Vc[(df * 16 + qc) * 64 +
                                                   ((k2 * 32 + kg * 8) ^ sw)];
                        ctx[df] = __builtin_amdgcn_mfma_f32_16x16x32_bf16(
                            vf.b, ap.b, ctx[df], 0, 0, 0);
                    }
                }
            }
            __syncthreads();   // drains staging vmcnt + separates buffers
        }
        // ---- normalize + store: lane holds q = q0w+qc, d = df*16+kg*4+r ----
        float inv = 1.f / lrun;
        unsigned short* Cq = Cb + (size_t)(q0w + qc) * E_DIM;
#pragma unroll
        for (int df = 0; df < 4; df++) {
            u16x4 o = { f2bf(ctx[df][0] * inv), f2bf(ctx[df][1] * inv),
                        f2bf(ctx[df][2] * inv), f2bf(ctx[df][3] * inv) };
            *(u16x4*)(Cq + df * 16 + kg * 4) = o;
        }
        // loop's final __syncthreads already separates pass 0 readers from
        // pass 1's prologue staging
    }
}

// ---------------- launcher ----------------
extern "C" void kernel_launch(void* const* d_in, const int* in_sizes, int n_in,
                              void* d_out, int out_size, void* d_ws, size_t ws_size,
                              hipStream_t stream)
{
    (void)in_sizes; (void)n_in; (void)out_size; (void)ws_size;
    const float* query = (const float*)d_in[0];
    const float* key_  = (const float*)d_in[1];
    const float* value = (const float*)d_in[2];
    const float* Wq = (const float*)d_in[5];
    const float* bq = (const float*)d_in[6];
    const float* Wk = (const float*)d_in[7];
    const float* bk = (const float*)d_in[8];
    const float* Wv = (const float*)d_in[9];
    const float* bv = (const float*)d_in[10];
    const float* Wo = (const float*)d_in[11];
    const float* bo = (const float*)d_in[12];
    float* out = (float*)d_out;

    char* ws = (char*)d_ws;
    const size_t MB = 1024 * 1024;
    unsigned short* Xq  = (unsigned short*)(ws + 0 * MB);
    unsigned short* Xk  = (unsigned short*)(ws + 8 * MB);
    unsigned short* Xv  = (unsigned short*)(ws + 16 * MB);
    unsigned short* Wqt = (unsigned short*)(ws + 24 * MB);
    unsigned short* Wkt = (unsigned short*)(ws + 26 * MB);
    unsigned short* Wvt = (unsigned short*)(ws + 28 * MB);
    unsigned short* Wot = (unsigned short*)(ws + 30 * MB);
    unsigned short* Qh  = (unsigned short*)(ws + 32 * MB);
    unsigned short* Kh  = (unsigned short*)(ws + 40 * MB);
    unsigned short* Vtp = (unsigned short*)(ws + 56 * MB);
    unsigned short* Ctx = (unsigned short*)(ws + 0 * MB);  // reuse Xq

    setup<<<dim3(2560), 256, 0, stream>>>(query, key_, value, Xq, Xk, Xv,
                                          Wq, Wk, Wv, Wo, Wqt, Wkt, Wvt, Wot);

    const float SCALE_Q = 0.18033688011112042f;  // log2(e) / sqrt(HD)=8
    gemm_qkv<<<dim3(32, 8, 3), 256, 0, stream>>>(Xq, Xk, Xv, Wqt, Wkt, Wvt,
                                                 bq, bk, bv, Qh, Kh, Vtp, SCALE_Q);

    attn_causal<<<dim3(256), 512, 0, stream>>>(Qh, Kh, Vtp, Ctx);

    gemm_o<<<dim3(32, 16), 256, 0, stream>>>(Ctx, Wot, bo, out);
}